// Round 6
// baseline (804.397 us; speedup 1.0000x reference)
//
#include <hip/hip_runtime.h>
#include <hip/hip_fp16.h>

#define LRELU_SLOPE 0.2f
#define BNEPS 1e-5f

__device__ __forceinline__ float lrelu(float x) { return x > 0.f ? x : LRELU_SLOPE * x; }

// ---------------- CSR build ----------------
__global__ void k_hist(const int* __restrict__ dst, int* __restrict__ deg, int E) {
  int i = blockIdx.x * 256 + threadIdx.x;
  if (i < E) atomicAdd(&deg[dst[i]], 1);
}

__global__ void k_scan1(const int* __restrict__ deg, int* __restrict__ rowstart,
                        int* __restrict__ bsum, int N) {
  __shared__ int lds[256];
  int t = threadIdx.x;
  int base = blockIdx.x * 1024 + t * 4;
  int v[4];
  int run = 0;
#pragma unroll
  for (int i = 0; i < 4; ++i) {
    int x = (base + i < N) ? deg[base + i] : 0;
    v[i] = run; run += x;
  }
  lds[t] = run;
  __syncthreads();
  for (int off = 1; off < 256; off <<= 1) {
    int x = (t >= off) ? lds[t - off] : 0;
    __syncthreads();
    lds[t] += x;
    __syncthreads();
  }
  int excl = lds[t] - run;
#pragma unroll
  for (int i = 0; i < 4; ++i)
    if (base + i < N) rowstart[base + i] = excl + v[i];
  if (t == 255) bsum[blockIdx.x] = lds[255];
}

__global__ void k_scan2(int* __restrict__ bsum, int nb) {
  __shared__ int lds[256];
  int t = threadIdx.x;
  int v = (t < nb) ? bsum[t] : 0;
  lds[t] = v;
  __syncthreads();
  for (int off = 1; off < 256; off <<= 1) {
    int x = (t >= off) ? lds[t - off] : 0;
    __syncthreads();
    lds[t] += x;
    __syncthreads();
  }
  if (t < nb) bsum[t] = lds[t] - v;   // exclusive
}

__global__ void k_scan3(int* __restrict__ rowstart, int* __restrict__ cursor,
                        const int* __restrict__ bsum, int N, int E) {
  int i = blockIdx.x * 256 + threadIdx.x;
  if (i < N) {
    int r = rowstart[i] + bsum[i >> 10];
    rowstart[i] = r;
    cursor[i] = r;
    if (i == 0) rowstart[N] = E;
  }
}

// Random 4B stores via plain store: each XCD's (non-coherent) L2 collects
// partially-dirty copies of csr lines -> ~16x partial-line writeback amp
// (measured 105.8 MB for a 6.4 MB array). atomicExch executes at the shared
// memory-side LLC instead -> all 16 slot-writes of a line merge there.
__global__ void k_scatter(const int* __restrict__ src, const int* __restrict__ dst,
                          int* __restrict__ cursor, int* __restrict__ csr, int E) {
  int i = blockIdx.x * 256 + threadIdx.x;
  if (i < E) {
    int d = dst[i];
    int pos = atomicAdd(&cursor[d], 1);
    atomicExch(&csr[pos], src[i]);   // fire-and-forget, LLC-side write
  }
}

// ---------------- Layer-1 GEMM (K=5) + attention logits ----------------
// h output stored fp16 (gather buffer for k_agg; only consumer).
__global__ __launch_bounds__(256) void k_gemm_l1(
    const float* __restrict__ x, const float* __restrict__ W,   // W: [64,5]
    const float* __restrict__ asrc, const float* __restrict__ adst,   // flat [64]
    __half* __restrict__ hg, float* __restrict__ alsrc, float* __restrict__ aldst, int N) {
  __shared__ float Ws[320];
  int t = threadIdx.x;
  for (int i = t; i < 320; i += 256) Ws[i] = W[i];   // block=256 < 320, must stride
  __syncthreads();
  int n = blockIdx.x * 4 + (t >> 6);
  int c = t & 63;
  if (n >= N) return;
  float acc = 0.f;
#pragma unroll
  for (int k = 0; k < 5; ++k) acc += x[n * 5 + k] * Ws[c * 5 + k];
  hg[(size_t)n * 64 + c] = __float2half_rn(acc);
  float ps = acc * asrc[c];
  float pd = acc * adst[c];
#pragma unroll
  for (int off = 1; off < 16; off <<= 1) {
    ps += __shfl_xor(ps, off, 64);
    pd += __shfl_xor(pd, off, 64);
  }
  if ((c & 15) == 0) {
    alsrc[n * 4 + (c >> 4)] = ps;
    aldst[n * 4 + (c >> 4)] = pd;
  }
}

// ---------------- K=64 GEMM (layers 2,3) + attention logits ----------------
// Block 256 threads: 128 nodes x 64 channels. Thread: 4 nodes x 8 channels.
// h output stored fp16.
template <int H>
__global__ __launch_bounds__(256) void k_gemm64(
    const float* __restrict__ xin, const float* __restrict__ W,   // W: [64,64] row-major [c][k]
    const float* __restrict__ asrc, const float* __restrict__ adst,   // flat [64]
    __half* __restrict__ hg, float* __restrict__ alsrc, float* __restrict__ aldst, int N) {
  __shared__ float Xs[64 * 132];   // [k][n], stride 132 -> b128 conflict-free
  __shared__ float Ws[64 * 65];    // [k][c], stride 65  -> scalar reads 2-way (free)
  int t = threadIdx.x;
  int nb0 = blockIdx.x * 128;

  for (int idx = t; idx < 4096; idx += 256) {
    int c = idx >> 6, k = idx & 63;
    Ws[k * 65 + c] = W[idx];
  }
  {
    int n = t & 127, kh = t >> 7;
    int gn = nb0 + n;
#pragma unroll
    for (int j = 0; j < 8; ++j) {
      int col = kh * 32 + j * 4;
      float4 xv = make_float4(0.f, 0.f, 0.f, 0.f);
      if (gn < N) xv = *(const float4*)&xin[(size_t)gn * 64 + col];
      Xs[(col + 0) * 132 + n] = xv.x;
      Xs[(col + 1) * 132 + n] = xv.y;
      Xs[(col + 2) * 132 + n] = xv.z;
      Xs[(col + 3) * 132 + n] = xv.w;
    }
  }
  __syncthreads();

  int cg = t & 7, ng = t >> 3;
  int c0 = cg * 8;
  float acc[4][8];
#pragma unroll
  for (int i = 0; i < 4; ++i)
#pragma unroll
    for (int j = 0; j < 8; ++j) acc[i][j] = 0.f;

  for (int k = 0; k < 64; ++k) {
    float4 xv = *(const float4*)&Xs[k * 132 + ng * 4];
    float w[8];
#pragma unroll
    for (int j = 0; j < 8; ++j) w[j] = Ws[k * 65 + c0 + j];
#pragma unroll
    for (int j = 0; j < 8; ++j) {
      acc[0][j] += xv.x * w[j];
      acc[1][j] += xv.y * w[j];
      acc[2][j] += xv.z * w[j];
      acc[3][j] += xv.w * w[j];
    }
  }

  float av[8], dv[8];
#pragma unroll
  for (int j = 0; j < 8; ++j) { av[j] = asrc[c0 + j]; dv[j] = adst[c0 + j]; }

#pragma unroll
  for (int i = 0; i < 4; ++i) {
    int n = nb0 + ng * 4 + i;
    float ps = 0.f, pd = 0.f;
#pragma unroll
    for (int j = 0; j < 8; ++j) { ps += acc[i][j] * av[j]; pd += acc[i][j] * dv[j]; }
    ps += __shfl_xor(ps, 1, 64);
    pd += __shfl_xor(pd, 1, 64);
    if (H == 1) {
      ps += __shfl_xor(ps, 2, 64); pd += __shfl_xor(pd, 2, 64);
      ps += __shfl_xor(ps, 4, 64); pd += __shfl_xor(pd, 4, 64);
    }
    if (n < N) {
      __half2 hv[4];
      hv[0] = __floats2half2_rn(acc[i][0], acc[i][1]);
      hv[1] = __floats2half2_rn(acc[i][2], acc[i][3]);
      hv[2] = __floats2half2_rn(acc[i][4], acc[i][5]);
      hv[3] = __floats2half2_rn(acc[i][6], acc[i][7]);
      *(float4*)&hg[(size_t)n * 64 + c0] = *(float4*)hv;   // 16 B, c0*2 bytes -> aligned
      if (H == 4) {
        if ((cg & 1) == 0) { alsrc[n * 4 + (cg >> 1)] = ps; aldst[n * 4 + (cg >> 1)] = pd; }
      } else {
        if (cg == 0) { alsrc[n] = ps; aldst[n] = pd; }
      }
    }
  }
}

// ---------------- edge-softmax aggregation + bias + BN (+ELU) ----------------
// One wave per destination node; lane = channel. Single-pass (bounded logits,
// raw exp safe in fp32). Chunk-32: e-lanes load TWO 16-slot batches of
// csr+alsrc+exp up front (32 gathers in flight), then shfl-broadcast loops.
// Broadcast p is wave-uniform -> p==0 skip is a scalar branch that elides
// OOB gathers entirely.
template <int HEADS, bool DOELU>
__global__ __launch_bounds__(256) void k_agg(
    const __half* __restrict__ hg, const float* __restrict__ alsrc, const float* __restrict__ aldst,
    const int* __restrict__ rowstart, const int* __restrict__ csr,
    const float* __restrict__ bias, const float* __restrict__ gamma, const float* __restrict__ beta,
    const float* __restrict__ mean, const float* __restrict__ var,
    float* __restrict__ out, int N) {
  int node = blockIdx.x * 4 + (threadIdx.x >> 6);
  if (node >= N) return;
  int lane = threadIdx.x & 63;
  int e16  = lane & 15;
  int head = (HEADS == 4) ? (lane >> 4) : 0;
  int grpbase = lane & 48;   // first lane of my 16-lane e-group

  float ad = aldst[node * HEADS + head];
  float pself = __expf(lrelu(alsrc[node * HEADS + head] + ad));
  float acc = pself * __half2float(hg[(size_t)node * 64 + lane]);
  float ssum = 0.f;

  int beg = rowstart[node], end = rowstart[node + 1];
  for (int jb = beg; jb < end; jb += 32) {
    int j0 = jb + e16, j1 = jb + 16 + e16;
    int s0 = 0, s1 = 0;
    float p0 = 0.f, p1 = 0.f;
    if (j0 < end) {
      s0 = csr[j0];
      p0 = __expf(lrelu(alsrc[s0 * HEADS + head] + ad));
    }
    if (j1 < end) {
      s1 = csr[j1];
      p1 = __expf(lrelu(alsrc[s1 * HEADS + head] + ad));
    }
    ssum += p0 + p1;
#pragma unroll
    for (int e = 0; e < 16; ++e) {
      float pj = __shfl(p0, grpbase + e, 64);
      if (pj != 0.f) {                       // wave-uniform: scalar skip of OOB slots
        int sj = __shfl(s0, grpbase + e, 64);
        acc += pj * __half2float(hg[(size_t)sj * 64 + lane]);
      }
    }
#pragma unroll
    for (int e = 0; e < 16; ++e) {
      float pj = __shfl(p1, grpbase + e, 64);
      if (pj != 0.f) {
        int sj = __shfl(s1, grpbase + e, 64);
        acc += pj * __half2float(hg[(size_t)sj * 64 + lane]);
      }
    }
  }
  // total ssum over the 16 e-lanes of the group
  ssum += __shfl_xor(ssum, 1, 64);
  ssum += __shfl_xor(ssum, 2, 64);
  ssum += __shfl_xor(ssum, 4, 64);
  ssum += __shfl_xor(ssum, 8, 64);
  ssum += pself;

  float v = acc / (ssum + 1e-16f) + bias[lane];
  v = (v - mean[lane]) * rsqrtf(var[lane] + BNEPS) * gamma[lane] + beta[lane];
  if (DOELU) v = v > 0.f ? v : __expf(v) - 1.f;
  out[(size_t)node * 64 + lane] = v;
}

// ---------------- mean pool ----------------
__global__ void k_pool(const float* __restrict__ h, float* __restrict__ pooled, int N) {
  __shared__ float red[4][64];
  int c = threadIdx.x & 63, r = threadIdx.x >> 6;
  float local = 0.f;
  for (int n = blockIdx.x * 4 + r; n < N; n += gridDim.x * 4)
    local += h[(size_t)n * 64 + c];
  red[r][c] = local;
  __syncthreads();
  if (r == 0) {
    float s = red[0][c] + red[1][c] + red[2][c] + red[3][c];
    atomicAdd(&pooled[c], s);
  }
}

// ---------------- MLP heads ----------------
__global__ void k_head(const float* __restrict__ pooled,
                       const float* __restrict__ cw1, const float* __restrict__ cb1,
                       const float* __restrict__ cw2, const float* __restrict__ cb2,
                       const float* __restrict__ rw1, const float* __restrict__ rb1,
                       const float* __restrict__ rw2, const float* __restrict__ rb2,
                       float* __restrict__ outp, float invN) {
  __shared__ float ps[64], hc[32], hr[32];
  int t = threadIdx.x;
  ps[t] = pooled[t] * invN;
  __syncthreads();
  if (t < 32) {
    float sc = cb1[t], sr = rb1[t];
    for (int c = 0; c < 64; ++c) {
      sc += ps[c] * cw1[t * 64 + c];
      sr += ps[c] * rw1[t * 64 + c];
    }
    hc[t] = sc > 0.f ? sc : 0.f;
    hr[t] = sr > 0.f ? sr : 0.f;
  }
  __syncthreads();
  if (t < 3) {
    float v = cb2[t];
    for (int j = 0; j < 32; ++j) v += hc[j] * cw2[t * 32 + j];
    outp[t] = v;
  } else if (t == 3) {
    float v = rb2[0];
    for (int j = 0; j < 32; ++j) v += hr[j] * rw2[j];
    outp[3] = v;
  }
}

static inline size_t align256(size_t x) { return (x + 255) & ~(size_t)255; }

extern "C" void kernel_launch(void* const* d_in, const int* in_sizes, int n_in,
                              void* d_out, int out_size, void* d_ws, size_t ws_size,
                              hipStream_t stream) {
  const float* x   = (const float*)d_in[0];
  const int*   ei  = (const int*)d_in[1];
  const float* W1  = (const float*)d_in[2];
  const float* a1s = (const float*)d_in[3];
  const float* a1d = (const float*)d_in[4];
  const float* b1  = (const float*)d_in[5];
  const float* W2  = (const float*)d_in[6];
  const float* a2s = (const float*)d_in[7];
  const float* a2d = (const float*)d_in[8];
  const float* b2  = (const float*)d_in[9];
  const float* W3  = (const float*)d_in[10];
  const float* a3s = (const float*)d_in[11];
  const float* a3d = (const float*)d_in[12];
  const float* b3  = (const float*)d_in[13];
  const float* bng = (const float*)d_in[14];
  const float* bnb = (const float*)d_in[15];
  const float* bnm = (const float*)d_in[16];
  const float* bnv = (const float*)d_in[17];
  const float* cw1 = (const float*)d_in[18];
  const float* cb1 = (const float*)d_in[19];
  const float* cw2 = (const float*)d_in[20];
  const float* cb2 = (const float*)d_in[21];
  const float* rw1 = (const float*)d_in[22];
  const float* rb1 = (const float*)d_in[23];
  const float* rw2 = (const float*)d_in[24];
  const float* rb2 = (const float*)d_in[25];

  const int N = in_sizes[0] / 5;
  const int E = in_sizes[1] / 2;
  const int* srcp = ei;
  const int* dstp = ei + E;

  // workspace carve-up
  char* p = (char*)d_ws;
  int* cursor   = (int*)p;  p += align256((size_t)N * 4);
  int* rowstart = (int*)p;  p += align256((size_t)(N + 1) * 4);
  int* csr      = (int*)p;  p += align256((size_t)E * 4);
  int* bsum     = (int*)p;  p += align256(1024 * 4);
  __half* hH    = (__half*)p; p += align256((size_t)N * 64 * 2);   // fp16 gather buffer
  float* hB     = (float*)p;  p += align256((size_t)N * 64 * 4);   // fp32 agg output
  float* alsrc  = (float*)p;  p += align256((size_t)N * 4 * 4);
  float* aldst  = (float*)p;  p += align256((size_t)N * 4 * 4);
  float* pooled = (float*)p;  p += align256(64 * 4);
  float* outp   = (float*)d_out;

  hipMemsetAsync(cursor, 0, (size_t)N * 4, stream);
  hipMemsetAsync(pooled, 0, 64 * 4, stream);

  const int nb = (N + 1023) / 1024;
  k_hist<<<(E + 255) / 256, 256, 0, stream>>>(dstp, cursor, E);
  k_scan1<<<nb, 256, 0, stream>>>(cursor, rowstart, bsum, N);
  k_scan2<<<1, 256, 0, stream>>>(bsum, nb);
  k_scan3<<<(N + 255) / 256, 256, 0, stream>>>(rowstart, cursor, bsum, N, E);
  k_scatter<<<(E + 255) / 256, 256, 0, stream>>>(srcp, dstp, cursor, csr, E);

  const int gNode4 = (N + 3) / 4;
  const int gNode128 = (N + 127) / 128;

  // Layer 1: x -> hH ; agg -> hB
  k_gemm_l1<<<gNode4, 256, 0, stream>>>(x, W1, a1s, a1d, hH, alsrc, aldst, N);
  k_agg<4, true><<<gNode4, 256, 0, stream>>>(hH, alsrc, aldst, rowstart, csr,
      b1, bng + 0, bnb + 0, bnm + 0, bnv + 0, hB, N);

  // Layer 2: hB -> hH ; agg -> hB
  k_gemm64<4><<<gNode128, 256, 0, stream>>>(hB, W2, a2s, a2d, hH, alsrc, aldst, N);
  k_agg<4, true><<<gNode4, 256, 0, stream>>>(hH, alsrc, aldst, rowstart, csr,
      b2, bng + 64, bnb + 64, bnm + 64, bnv + 64, hB, N);

  // Layer 3: hB -> hH ; agg -> hB (no ELU)
  k_gemm64<1><<<gNode128, 256, 0, stream>>>(hB, W3, a3s, a3d, hH, alsrc, aldst, N);
  k_agg<1, false><<<gNode4, 256, 0, stream>>>(hH, alsrc, aldst, rowstart, csr,
      b3, bng + 128, bnb + 128, bnm + 128, bnv + 128, hB, N);

  k_pool<<<512, 256, 0, stream>>>(hB, pooled, N);
  k_head<<<1, 64, 0, stream>>>(pooled, cw1, cb1, cw2, cb2, rw1, rb1, rw2, rb2,
                               outp, 1.0f / (float)N);
}

// Round 7
// 519.162 us; speedup vs baseline: 1.5494x; 1.5494x over previous
//
#include <hip/hip_runtime.h>
#include <hip/hip_fp16.h>

#define LRELU_SLOPE 0.2f
#define BNEPS 1e-5f
#define BK 128      // max dst-buckets (dst>>10; N=100k -> 98 used)
#define TILE 2048   // edges per k_bucket block

__device__ __forceinline__ float lrelu(float x) { return x > 0.f ? x : LRELU_SLOPE * x; }

// ---------------- CSR build ----------------
__global__ void k_hist(const int* __restrict__ dst, int* __restrict__ deg, int E) {
  int i = blockIdx.x * 256 + threadIdx.x;
  if (i < E) atomicAdd(&deg[dst[i]], 1);
}

__global__ void k_scan1(const int* __restrict__ deg, int* __restrict__ rowstart,
                        int* __restrict__ bsum, int N) {
  __shared__ int lds[256];
  int t = threadIdx.x;
  int base = blockIdx.x * 1024 + t * 4;
  int v[4];
  int run = 0;
#pragma unroll
  for (int i = 0; i < 4; ++i) {
    int x = (base + i < N) ? deg[base + i] : 0;
    v[i] = run; run += x;
  }
  lds[t] = run;
  __syncthreads();
  for (int off = 1; off < 256; off <<= 1) {
    int x = (t >= off) ? lds[t - off] : 0;
    __syncthreads();
    lds[t] += x;
    __syncthreads();
  }
  int excl = lds[t] - run;
#pragma unroll
  for (int i = 0; i < 4; ++i)
    if (base + i < N) rowstart[base + i] = excl + v[i];
  if (t == 255) bsum[blockIdx.x] = lds[255];
}

__global__ void k_scan2(int* __restrict__ bsum, int nb) {
  __shared__ int lds[256];
  int t = threadIdx.x;
  int v = (t < nb) ? bsum[t] : 0;
  lds[t] = v;
  __syncthreads();
  for (int off = 1; off < 256; off <<= 1) {
    int x = (t >= off) ? lds[t - off] : 0;
    __syncthreads();
    lds[t] += x;
    __syncthreads();
  }
  if (t < nb) bsum[t] = lds[t] - v;   // exclusive
}

// finalize rowstart; also init per-bucket staging cursors (bucket = node>>10)
__global__ void k_scan3(int* __restrict__ rowstart, int* __restrict__ cursorB,
                        const int* __restrict__ bsum, int N, int E) {
  int i = blockIdx.x * 256 + threadIdx.x;
  if (i < N) {
    int r = rowstart[i] + bsum[i >> 10];
    rowstart[i] = r;
    if ((i & 1023) == 0) cursorB[i >> 10] = r;   // bucket base in csr == staging base
    if (i == 0) rowstart[N] = E;
  }
}

// ---------------- two-pass bucketed edge sort (replaces random scatter) ----
// Pass 1: group edges by 1024-node dst-bucket into staging. All global writes
// are contiguous runs (reordered through LDS) -> no partial-line writeback amp.
__global__ __launch_bounds__(256) void k_bucket(
    const int* __restrict__ src, const int* __restrict__ dst,
    int* __restrict__ cursorB, int2* __restrict__ stg, int E, int NB) {
  __shared__ int cnt[BK];
  __shared__ int off[BK];
  __shared__ int base[BK];
  __shared__ int2 pair[TILE];
  __shared__ int ga[TILE];
  int t = threadIdx.x;
  int tb = blockIdx.x * TILE;

  for (int i = t; i < BK; i += 256) cnt[i] = 0;
  __syncthreads();

  int mys[8], myd[8], myb[8], myrank[8];
#pragma unroll
  for (int k = 0; k < 8; ++k) {
    int e = tb + k * 256 + t;
    myd[k] = -1;
    if (e < E) {
      mys[k] = src[e];
      myd[k] = dst[e];
      myb[k] = myd[k] >> 10;
      myrank[k] = atomicAdd(&cnt[myb[k]], 1);
    }
  }
  __syncthreads();
  // exclusive scan of cnt[0..BK) + reserve global per-bucket ranges
  if (t < BK) off[t] = cnt[t];
  __syncthreads();
  for (int o = 1; o < BK; o <<= 1) {
    int x = 0;
    if (t < BK && t >= o) x = off[t - o];
    __syncthreads();
    if (t < BK) off[t] += x;
    __syncthreads();
  }
  if (t < BK) {
    int c = cnt[t];
    off[t] -= c;                                      // exclusive
    base[t] = (c > 0) ? atomicAdd(&cursorB[t], c) : 0;
  }
  __syncthreads();
  // reorder tile by bucket in LDS; record each slot's global address
#pragma unroll
  for (int k = 0; k < 8; ++k) {
    if (myd[k] >= 0) {
      int p = off[myb[k]] + myrank[k];
      pair[p] = make_int2(mys[k], myd[k]);
      ga[p] = base[myb[k]] + myrank[k];
    }
  }
  __syncthreads();
  int nvalid = min(TILE, E - tb);
#pragma unroll
  for (int k = 0; k < 8; ++k) {
    int p = k * 256 + t;
    if (p < nvalid) stg[ga[p]] = pair[p];   // contiguous runs per bucket
  }
}

// Pass 2: one block per bucket. Per-node cursors in LDS (fast atomics); csr
// writes confined to this bucket's ~65 KB region written by ONE block/XCD ->
// lines become fully dirty, no cross-XCD partial writebacks.
__global__ __launch_bounds__(256) void k_fine(
    const int2* __restrict__ stg, const int* __restrict__ rowstart,
    int* __restrict__ csr, int N) {
  __shared__ int cur[1024];
  int b = blockIdx.x;
  int n0 = b << 10;
  int t = threadIdx.x;
  for (int i = t; i < 1024; i += 256) {
    int n = n0 + i;
    cur[i] = (n < N) ? rowstart[n] : 0;
  }
  __syncthreads();
  int beg = rowstart[n0];
  int end = rowstart[min(n0 + 1024, N)];
  for (int j = beg + t; j < end; j += 256) {
    int2 e = stg[j];
    int pos = atomicAdd(&cur[e.y - n0], 1);
    csr[pos] = e.x;
  }
}

// ---------------- Layer-1 GEMM (K=5) + attention logits ----------------
__global__ __launch_bounds__(256) void k_gemm_l1(
    const float* __restrict__ x, const float* __restrict__ W,   // W: [64,5]
    const float* __restrict__ asrc, const float* __restrict__ adst,   // flat [64]
    __half* __restrict__ hg, float* __restrict__ alsrc, float* __restrict__ aldst, int N) {
  __shared__ float Ws[320];
  int t = threadIdx.x;
  for (int i = t; i < 320; i += 256) Ws[i] = W[i];
  __syncthreads();
  int n = blockIdx.x * 4 + (t >> 6);
  int c = t & 63;
  if (n >= N) return;
  float acc = 0.f;
#pragma unroll
  for (int k = 0; k < 5; ++k) acc += x[n * 5 + k] * Ws[c * 5 + k];
  hg[(size_t)n * 64 + c] = __float2half_rn(acc);
  float ps = acc * asrc[c];
  float pd = acc * adst[c];
#pragma unroll
  for (int off = 1; off < 16; off <<= 1) {
    ps += __shfl_xor(ps, off, 64);
    pd += __shfl_xor(pd, off, 64);
  }
  if ((c & 15) == 0) {
    alsrc[n * 4 + (c >> 4)] = ps;
    aldst[n * 4 + (c >> 4)] = pd;
  }
}

// ---------------- K=64 GEMM (layers 2,3) + attention logits ----------------
template <int H>
__global__ __launch_bounds__(256) void k_gemm64(
    const float* __restrict__ xin, const float* __restrict__ W,
    const float* __restrict__ asrc, const float* __restrict__ adst,
    __half* __restrict__ hg, float* __restrict__ alsrc, float* __restrict__ aldst, int N) {
  __shared__ float Xs[64 * 132];
  __shared__ float Ws[64 * 65];
  int t = threadIdx.x;
  int nb0 = blockIdx.x * 128;

  for (int idx = t; idx < 4096; idx += 256) {
    int c = idx >> 6, k = idx & 63;
    Ws[k * 65 + c] = W[idx];
  }
  {
    int n = t & 127, kh = t >> 7;
    int gn = nb0 + n;
#pragma unroll
    for (int j = 0; j < 8; ++j) {
      int col = kh * 32 + j * 4;
      float4 xv = make_float4(0.f, 0.f, 0.f, 0.f);
      if (gn < N) xv = *(const float4*)&xin[(size_t)gn * 64 + col];
      Xs[(col + 0) * 132 + n] = xv.x;
      Xs[(col + 1) * 132 + n] = xv.y;
      Xs[(col + 2) * 132 + n] = xv.z;
      Xs[(col + 3) * 132 + n] = xv.w;
    }
  }
  __syncthreads();

  int cg = t & 7, ng = t >> 3;
  int c0 = cg * 8;
  float acc[4][8];
#pragma unroll
  for (int i = 0; i < 4; ++i)
#pragma unroll
    for (int j = 0; j < 8; ++j) acc[i][j] = 0.f;

  for (int k = 0; k < 64; ++k) {
    float4 xv = *(const float4*)&Xs[k * 132 + ng * 4];
    float w[8];
#pragma unroll
    for (int j = 0; j < 8; ++j) w[j] = Ws[k * 65 + c0 + j];
#pragma unroll
    for (int j = 0; j < 8; ++j) {
      acc[0][j] += xv.x * w[j];
      acc[1][j] += xv.y * w[j];
      acc[2][j] += xv.z * w[j];
      acc[3][j] += xv.w * w[j];
    }
  }

  float av[8], dv[8];
#pragma unroll
  for (int j = 0; j < 8; ++j) { av[j] = asrc[c0 + j]; dv[j] = adst[c0 + j]; }

#pragma unroll
  for (int i = 0; i < 4; ++i) {
    int n = nb0 + ng * 4 + i;
    float ps = 0.f, pd = 0.f;
#pragma unroll
    for (int j = 0; j < 8; ++j) { ps += acc[i][j] * av[j]; pd += acc[i][j] * dv[j]; }
    ps += __shfl_xor(ps, 1, 64);
    pd += __shfl_xor(pd, 1, 64);
    if (H == 1) {
      ps += __shfl_xor(ps, 2, 64); pd += __shfl_xor(pd, 2, 64);
      ps += __shfl_xor(ps, 4, 64); pd += __shfl_xor(pd, 4, 64);
    }
    if (n < N) {
      __half2 hv[4];
      hv[0] = __floats2half2_rn(acc[i][0], acc[i][1]);
      hv[1] = __floats2half2_rn(acc[i][2], acc[i][3]);
      hv[2] = __floats2half2_rn(acc[i][4], acc[i][5]);
      hv[3] = __floats2half2_rn(acc[i][6], acc[i][7]);
      *(float4*)&hg[(size_t)n * 64 + c0] = *(float4*)hv;
      if (H == 4) {
        if ((cg & 1) == 0) { alsrc[n * 4 + (cg >> 1)] = ps; aldst[n * 4 + (cg >> 1)] = pd; }
      } else {
        if (cg == 0) { alsrc[n] = ps; aldst[n] = pd; }
      }
    }
  }
}

// ---------------- edge-softmax aggregation + bias + BN (+ELU) ----------------
// Round-5 form (chunk-16, branchless) — chunk-32 + divergent skip regressed (R6).
template <int HEADS, bool DOELU>
__global__ __launch_bounds__(256) void k_agg(
    const __half* __restrict__ hg, const float* __restrict__ alsrc, const float* __restrict__ aldst,
    const int* __restrict__ rowstart, const int* __restrict__ csr,
    const float* __restrict__ bias, const float* __restrict__ gamma, const float* __restrict__ beta,
    const float* __restrict__ mean, const float* __restrict__ var,
    float* __restrict__ out, int N) {
  int node = blockIdx.x * 4 + (threadIdx.x >> 6);
  if (node >= N) return;
  int lane = threadIdx.x & 63;
  int e16  = lane & 15;
  int head = (HEADS == 4) ? (lane >> 4) : 0;
  int grpbase = lane & 48;

  float ad = aldst[node * HEADS + head];
  float pself = __expf(lrelu(alsrc[node * HEADS + head] + ad));
  float acc = pself * __half2float(hg[(size_t)node * 64 + lane]);
  float ssum = 0.f;

  int beg = rowstart[node], end = rowstart[node + 1];
  for (int jb = beg; jb < end; jb += 16) {
    int j = jb + e16;
    int s = 0;
    float p = 0.f;
    if (j < end) {
      s = csr[j];
      p = __expf(lrelu(alsrc[s * HEADS + head] + ad));
    }
    ssum += p;
#pragma unroll
    for (int e = 0; e < 16; ++e) {
      float pj = __shfl(p, grpbase + e, 64);
      int   sj = __shfl(s, grpbase + e, 64);
      acc += pj * __half2float(hg[(size_t)sj * 64 + lane]);  // OOB: p=0 — harmless
    }
  }
  ssum += __shfl_xor(ssum, 1, 64);
  ssum += __shfl_xor(ssum, 2, 64);
  ssum += __shfl_xor(ssum, 4, 64);
  ssum += __shfl_xor(ssum, 8, 64);
  ssum += pself;

  float v = acc / (ssum + 1e-16f) + bias[lane];
  v = (v - mean[lane]) * rsqrtf(var[lane] + BNEPS) * gamma[lane] + beta[lane];
  if (DOELU) v = v > 0.f ? v : __expf(v) - 1.f;
  out[(size_t)node * 64 + lane] = v;
}

// ---------------- mean pool ----------------
__global__ void k_pool(const float* __restrict__ h, float* __restrict__ pooled, int N) {
  __shared__ float red[4][64];
  int c = threadIdx.x & 63, r = threadIdx.x >> 6;
  float local = 0.f;
  for (int n = blockIdx.x * 4 + r; n < N; n += gridDim.x * 4)
    local += h[(size_t)n * 64 + c];
  red[r][c] = local;
  __syncthreads();
  if (r == 0) {
    float s = red[0][c] + red[1][c] + red[2][c] + red[3][c];
    atomicAdd(&pooled[c], s);
  }
}

// ---------------- MLP heads ----------------
__global__ void k_head(const float* __restrict__ pooled,
                       const float* __restrict__ cw1, const float* __restrict__ cb1,
                       const float* __restrict__ cw2, const float* __restrict__ cb2,
                       const float* __restrict__ rw1, const float* __restrict__ rb1,
                       const float* __restrict__ rw2, const float* __restrict__ rb2,
                       float* __restrict__ outp, float invN) {
  __shared__ float ps[64], hc[32], hr[32];
  int t = threadIdx.x;
  ps[t] = pooled[t] * invN;
  __syncthreads();
  if (t < 32) {
    float sc = cb1[t], sr = rb1[t];
    for (int c = 0; c < 64; ++c) {
      sc += ps[c] * cw1[t * 64 + c];
      sr += ps[c] * rw1[t * 64 + c];
    }
    hc[t] = sc > 0.f ? sc : 0.f;
    hr[t] = sr > 0.f ? sr : 0.f;
  }
  __syncthreads();
  if (t < 3) {
    float v = cb2[t];
    for (int j = 0; j < 32; ++j) v += hc[j] * cw2[t * 32 + j];
    outp[t] = v;
  } else if (t == 3) {
    float v = rb2[0];
    for (int j = 0; j < 32; ++j) v += hr[j] * rw2[j];
    outp[3] = v;
  }
}

static inline size_t align256(size_t x) { return (x + 255) & ~(size_t)255; }

extern "C" void kernel_launch(void* const* d_in, const int* in_sizes, int n_in,
                              void* d_out, int out_size, void* d_ws, size_t ws_size,
                              hipStream_t stream) {
  const float* x   = (const float*)d_in[0];
  const int*   ei  = (const int*)d_in[1];
  const float* W1  = (const float*)d_in[2];
  const float* a1s = (const float*)d_in[3];
  const float* a1d = (const float*)d_in[4];
  const float* b1  = (const float*)d_in[5];
  const float* W2  = (const float*)d_in[6];
  const float* a2s = (const float*)d_in[7];
  const float* a2d = (const float*)d_in[8];
  const float* b2  = (const float*)d_in[9];
  const float* W3  = (const float*)d_in[10];
  const float* a3s = (const float*)d_in[11];
  const float* a3d = (const float*)d_in[12];
  const float* b3  = (const float*)d_in[13];
  const float* bng = (const float*)d_in[14];
  const float* bnb = (const float*)d_in[15];
  const float* bnm = (const float*)d_in[16];
  const float* bnv = (const float*)d_in[17];
  const float* cw1 = (const float*)d_in[18];
  const float* cb1 = (const float*)d_in[19];
  const float* cw2 = (const float*)d_in[20];
  const float* cb2 = (const float*)d_in[21];
  const float* rw1 = (const float*)d_in[22];
  const float* rb1 = (const float*)d_in[23];
  const float* rw2 = (const float*)d_in[24];
  const float* rb2 = (const float*)d_in[25];

  const int N = in_sizes[0] / 5;
  const int E = in_sizes[1] / 2;
  const int* srcp = ei;
  const int* dstp = ei + E;
  const int NB = (N + 1023) >> 10;

  // workspace carve-up
  char* p = (char*)d_ws;
  int* deg      = (int*)p;  p += align256((size_t)N * 4);
  int* rowstart = (int*)p;  p += align256((size_t)(N + 1) * 4);
  int* csr      = (int*)p;  p += align256((size_t)E * 4);
  int* bsum     = (int*)p;  p += align256(1024 * 4);
  int* cursorB  = (int*)p;  p += align256(BK * 4);
  __half* hH    = (__half*)p; p += align256((size_t)N * 64 * 2);   // fp16 gather buffer
  float* hB     = (float*)p;  p += align256((size_t)N * 64 * 4);   // fp32 agg output
  float* alsrc  = (float*)p;  p += align256((size_t)N * 4 * 4);
  float* aldst  = (float*)p;  p += align256((size_t)N * 4 * 4);
  float* pooled = (float*)p;  p += align256(64 * 4);
  float* outp   = (float*)d_out;
  // staging for bucket sort aliases hB (12.8 MB < 25.6 MB; dead until k_agg L1)
  int2* stg     = (int2*)hB;

  hipMemsetAsync(deg, 0, (size_t)N * 4, stream);
  hipMemsetAsync(pooled, 0, 64 * 4, stream);

  const int nb = (N + 1023) / 1024;
  k_hist<<<(E + 255) / 256, 256, 0, stream>>>(dstp, deg, E);
  k_scan1<<<nb, 256, 0, stream>>>(deg, rowstart, bsum, N);
  k_scan2<<<1, 256, 0, stream>>>(bsum, nb);
  k_scan3<<<(N + 255) / 256, 256, 0, stream>>>(rowstart, cursorB, bsum, N, E);
  k_bucket<<<(E + TILE - 1) / TILE, 256, 0, stream>>>(srcp, dstp, cursorB, stg, E, NB);
  k_fine<<<NB, 256, 0, stream>>>(stg, rowstart, csr, N);

  const int gNode4 = (N + 3) / 4;
  const int gNode128 = (N + 127) / 128;

  // Layer 1: x -> hH ; agg -> hB
  k_gemm_l1<<<gNode4, 256, 0, stream>>>(x, W1, a1s, a1d, hH, alsrc, aldst, N);
  k_agg<4, true><<<gNode4, 256, 0, stream>>>(hH, alsrc, aldst, rowstart, csr,
      b1, bng + 0, bnb + 0, bnm + 0, bnv + 0, hB, N);

  // Layer 2: hB -> hH ; agg -> hB
  k_gemm64<4><<<gNode128, 256, 0, stream>>>(hB, W2, a2s, a2d, hH, alsrc, aldst, N);
  k_agg<4, true><<<gNode4, 256, 0, stream>>>(hH, alsrc, aldst, rowstart, csr,
      b2, bng + 64, bnb + 64, bnm + 64, bnv + 64, hB, N);

  // Layer 3: hB -> hH ; agg -> hB (no ELU)
  k_gemm64<1><<<gNode128, 256, 0, stream>>>(hB, W3, a3s, a3d, hH, alsrc, aldst, N);
  k_agg<1, false><<<gNode4, 256, 0, stream>>>(hH, alsrc, aldst, rowstart, csr,
      b3, bng + 128, bnb + 128, bnm + 128, bnv + 128, hB, N);

  k_pool<<<512, 256, 0, stream>>>(hB, pooled, N);
  k_head<<<1, 64, 0, stream>>>(pooled, cw1, cb1, cw2, cb2, rw1, rb1, rw2, rb2,
                               outp, 1.0f / (float)N);
}

// Round 8
// 492.133 us; speedup vs baseline: 1.6345x; 1.0549x over previous
//
#include <hip/hip_runtime.h>
#include <hip/hip_fp16.h>

#define LRELU_SLOPE 0.2f
#define BNEPS 1e-5f
#define BK 128      // max dst-buckets (dst>>10; N=100k -> 98 used)
#define TILE 2048   // edges per k_bucket block

__device__ __forceinline__ float lrelu(float x) { return x > 0.f ? x : LRELU_SLOPE * x; }

// ---------------- bucket-size count (streaming, LDS hist; no random global atomics)
__global__ void k_count(const int* __restrict__ dst, int* __restrict__ bcnt, int E) {
  __shared__ int lc[BK];
  int t = threadIdx.x;
  for (int i = t; i < BK; i += 256) lc[i] = 0;
  __syncthreads();
  for (int i = blockIdx.x * 256 + t; i < E; i += gridDim.x * 256)
    atomicAdd(&lc[dst[i] >> 10], 1);
  __syncthreads();
  for (int i = t; i < BK; i += 256)
    if (lc[i]) atomicAdd(&bcnt[i], lc[i]);
}

// 1 block x BK threads: exclusive scan of bucket counts -> bases + cursors
__global__ void k_bscan(const int* __restrict__ bcnt, int* __restrict__ bucketBase,
                        int* __restrict__ cursorB, int E) {
  __shared__ int lds[BK];
  int t = threadIdx.x;
  int v = bcnt[t];
  lds[t] = v;
  __syncthreads();
  for (int off = 1; off < BK; off <<= 1) {
    int x = (t >= off) ? lds[t - off] : 0;
    __syncthreads();
    lds[t] += x;
    __syncthreads();
  }
  int excl = lds[t] - v;   // buckets >= NB have v=0 -> excl = E
  bucketBase[t] = excl;
  cursorB[t] = excl;
  if (t == BK - 1) bucketBase[BK] = E;
}

// ---------------- two-pass bucketed edge sort ----------------
// Pass 1: group edges by 1024-node dst-bucket into staging (contiguous runs).
__global__ __launch_bounds__(256) void k_bucket(
    const int* __restrict__ src, const int* __restrict__ dst,
    int* __restrict__ cursorB, int2* __restrict__ stg, int E) {
  __shared__ int cnt[BK];
  __shared__ int off[BK];
  __shared__ int base[BK];
  __shared__ int2 pair[TILE];
  __shared__ int ga[TILE];
  int t = threadIdx.x;
  int tb = blockIdx.x * TILE;

  for (int i = t; i < BK; i += 256) cnt[i] = 0;
  __syncthreads();

  int mys[8], myd[8], myb[8], myrank[8];
#pragma unroll
  for (int k = 0; k < 8; ++k) {
    int e = tb + k * 256 + t;
    myd[k] = -1;
    if (e < E) {
      mys[k] = src[e];
      myd[k] = dst[e];
      myb[k] = myd[k] >> 10;
      myrank[k] = atomicAdd(&cnt[myb[k]], 1);
    }
  }
  __syncthreads();
  if (t < BK) off[t] = cnt[t];
  __syncthreads();
  for (int o = 1; o < BK; o <<= 1) {
    int x = 0;
    if (t < BK && t >= o) x = off[t - o];
    __syncthreads();
    if (t < BK) off[t] += x;
    __syncthreads();
  }
  if (t < BK) {
    int c = cnt[t];
    off[t] -= c;                                      // exclusive
    base[t] = (c > 0) ? atomicAdd(&cursorB[t], c) : 0;
  }
  __syncthreads();
#pragma unroll
  for (int k = 0; k < 8; ++k) {
    if (myd[k] >= 0) {
      int p = off[myb[k]] + myrank[k];
      pair[p] = make_int2(mys[k], myd[k]);
      ga[p] = base[myb[k]] + myrank[k];
    }
  }
  __syncthreads();
  int nvalid = min(TILE, E - tb);
#pragma unroll
  for (int k = 0; k < 8; ++k) {
    int p = k * 256 + t;
    if (p < nvalid) stg[ga[p]] = pair[p];   // contiguous runs per bucket
  }
}

// Pass 2: one block per bucket. Computes per-node degrees (LDS hist) + local
// scan -> writes rowstart (coalesced) AND scatters csr with LDS cursors.
// Replaces the old k_hist + global scans.
__global__ __launch_bounds__(256) void k_fine(
    const int2* __restrict__ stg, const int* __restrict__ bucketBase,
    int* __restrict__ rowstart, int* __restrict__ csr, int N, int NB) {
  __shared__ int cnt[1024];
  __shared__ int sc[256];
  int b = blockIdx.x;
  int n0 = b << 10;
  int t = threadIdx.x;
  int beg = bucketBase[b], end = bucketBase[b + 1];

  for (int i = t; i < 1024; i += 256) cnt[i] = 0;
  __syncthreads();
  for (int j = beg + t; j < end; j += 256)
    atomicAdd(&cnt[stg[j].y - n0], 1);
  __syncthreads();

  // exclusive scan of cnt[0..1024): each thread owns 4 entries
  int v[4];
  int run = 0;
  int b4 = t * 4;
#pragma unroll
  for (int i = 0; i < 4; ++i) { v[i] = run; run += cnt[b4 + i]; }
  sc[t] = run;
  __syncthreads();
  for (int off = 1; off < 256; off <<= 1) {
    int x = (t >= off) ? sc[t - off] : 0;
    __syncthreads();
    sc[t] += x;
    __syncthreads();
  }
  int excl = sc[t] - run;
#pragma unroll
  for (int i = 0; i < 4; ++i) {
    int local = b4 + i;
    int rs = beg + excl + v[i];
    int n = n0 + local;
    if (n < N) rowstart[n] = rs;
    cnt[local] = rs;                       // becomes the cursor
  }
  if (b == NB - 1 && t == 0) rowstart[N] = end;
  __syncthreads();

  for (int j = beg + t; j < end; j += 256) {
    int2 e = stg[j];
    int pos = atomicAdd(&cnt[e.y - n0], 1);
    csr[pos] = e.x;                        // confined to this bucket's region
  }
}

// ---------------- Layer-1 GEMM (K=5) + attention logits ----------------
__global__ __launch_bounds__(256) void k_gemm_l1(
    const float* __restrict__ x, const float* __restrict__ W,   // W: [64,5]
    const float* __restrict__ asrc, const float* __restrict__ adst,   // flat [64]
    __half* __restrict__ hg, float* __restrict__ alsrc, float* __restrict__ aldst, int N) {
  __shared__ float Ws[320];
  int t = threadIdx.x;
  for (int i = t; i < 320; i += 256) Ws[i] = W[i];
  __syncthreads();
  int n = blockIdx.x * 4 + (t >> 6);
  int c = t & 63;
  if (n >= N) return;
  float acc = 0.f;
#pragma unroll
  for (int k = 0; k < 5; ++k) acc += x[n * 5 + k] * Ws[c * 5 + k];
  hg[(size_t)n * 64 + c] = __float2half_rn(acc);
  float ps = acc * asrc[c];
  float pd = acc * adst[c];
#pragma unroll
  for (int off = 1; off < 16; off <<= 1) {
    ps += __shfl_xor(ps, off, 64);
    pd += __shfl_xor(pd, off, 64);
  }
  if ((c & 15) == 0) {
    alsrc[n * 4 + (c >> 4)] = ps;
    aldst[n * 4 + (c >> 4)] = pd;
  }
}

// ---------------- K=64 GEMM (layers 2,3) + attention logits ----------------
template <int H>
__global__ __launch_bounds__(256) void k_gemm64(
    const float* __restrict__ xin, const float* __restrict__ W,
    const float* __restrict__ asrc, const float* __restrict__ adst,
    __half* __restrict__ hg, float* __restrict__ alsrc, float* __restrict__ aldst, int N) {
  __shared__ float Xs[64 * 132];
  __shared__ float Ws[64 * 65];
  int t = threadIdx.x;
  int nb0 = blockIdx.x * 128;

  for (int idx = t; idx < 4096; idx += 256) {
    int c = idx >> 6, k = idx & 63;
    Ws[k * 65 + c] = W[idx];
  }
  {
    int n = t & 127, kh = t >> 7;
    int gn = nb0 + n;
#pragma unroll
    for (int j = 0; j < 8; ++j) {
      int col = kh * 32 + j * 4;
      float4 xv = make_float4(0.f, 0.f, 0.f, 0.f);
      if (gn < N) xv = *(const float4*)&xin[(size_t)gn * 64 + col];
      Xs[(col + 0) * 132 + n] = xv.x;
      Xs[(col + 1) * 132 + n] = xv.y;
      Xs[(col + 2) * 132 + n] = xv.z;
      Xs[(col + 3) * 132 + n] = xv.w;
    }
  }
  __syncthreads();

  int cg = t & 7, ng = t >> 3;
  int c0 = cg * 8;
  float acc[4][8];
#pragma unroll
  for (int i = 0; i < 4; ++i)
#pragma unroll
    for (int j = 0; j < 8; ++j) acc[i][j] = 0.f;

  for (int k = 0; k < 64; ++k) {
    float4 xv = *(const float4*)&Xs[k * 132 + ng * 4];
    float w[8];
#pragma unroll
    for (int j = 0; j < 8; ++j) w[j] = Ws[k * 65 + c0 + j];
#pragma unroll
    for (int j = 0; j < 8; ++j) {
      acc[0][j] += xv.x * w[j];
      acc[1][j] += xv.y * w[j];
      acc[2][j] += xv.z * w[j];
      acc[3][j] += xv.w * w[j];
    }
  }

  float av[8], dv[8];
#pragma unroll
  for (int j = 0; j < 8; ++j) { av[j] = asrc[c0 + j]; dv[j] = adst[c0 + j]; }

#pragma unroll
  for (int i = 0; i < 4; ++i) {
    int n = nb0 + ng * 4 + i;
    float ps = 0.f, pd = 0.f;
#pragma unroll
    for (int j = 0; j < 8; ++j) { ps += acc[i][j] * av[j]; pd += acc[i][j] * dv[j]; }
    ps += __shfl_xor(ps, 1, 64);
    pd += __shfl_xor(pd, 1, 64);
    if (H == 1) {
      ps += __shfl_xor(ps, 2, 64); pd += __shfl_xor(pd, 2, 64);
      ps += __shfl_xor(ps, 4, 64); pd += __shfl_xor(pd, 4, 64);
    }
    if (n < N) {
      __half2 hv[4];
      hv[0] = __floats2half2_rn(acc[i][0], acc[i][1]);
      hv[1] = __floats2half2_rn(acc[i][2], acc[i][3]);
      hv[2] = __floats2half2_rn(acc[i][4], acc[i][5]);
      hv[3] = __floats2half2_rn(acc[i][6], acc[i][7]);
      *(float4*)&hg[(size_t)n * 64 + c0] = *(float4*)hv;
      if (H == 4) {
        if ((cg & 1) == 0) { alsrc[n * 4 + (cg >> 1)] = ps; aldst[n * 4 + (cg >> 1)] = pd; }
      } else {
        if (cg == 0) { alsrc[n] = ps; aldst[n] = pd; }
      }
    }
  }
}

// ---------------- edge-softmax aggregation + bias + BN (+ELU) ----------------
// R5 form (chunk-16, branchless). DOPOOL: skip writing out; accumulate the
// graph mean-pool partials instead (layer 3's output feeds only the pool).
template <int HEADS, bool DOELU, bool DOPOOL>
__global__ __launch_bounds__(256) void k_agg(
    const __half* __restrict__ hg, const float* __restrict__ alsrc, const float* __restrict__ aldst,
    const int* __restrict__ rowstart, const int* __restrict__ csr,
    const float* __restrict__ bias, const float* __restrict__ gamma, const float* __restrict__ beta,
    const float* __restrict__ mean, const float* __restrict__ var,
    float* __restrict__ out, float* __restrict__ pooled, int N) {
  int lane = threadIdx.x & 63;
  int e16  = lane & 15;
  int head = (HEADS == 4) ? (lane >> 4) : 0;
  int grpbase = lane & 48;
  float psum = 0.f;

  for (int node = blockIdx.x * 4 + (threadIdx.x >> 6); node < N; node += gridDim.x * 4) {
    float ad = aldst[node * HEADS + head];
    float pself = __expf(lrelu(alsrc[node * HEADS + head] + ad));
    float acc = pself * __half2float(hg[(size_t)node * 64 + lane]);
    float ssum = 0.f;

    int beg = rowstart[node], end = rowstart[node + 1];
    for (int jb = beg; jb < end; jb += 16) {
      int j = jb + e16;
      int s = 0;
      float p = 0.f;
      if (j < end) {
        s = csr[j];
        p = __expf(lrelu(alsrc[s * HEADS + head] + ad));
      }
      ssum += p;
#pragma unroll
      for (int e = 0; e < 16; ++e) {
        float pj = __shfl(p, grpbase + e, 64);
        int   sj = __shfl(s, grpbase + e, 64);
        acc += pj * __half2float(hg[(size_t)sj * 64 + lane]);  // OOB: p=0 — harmless
      }
    }
    ssum += __shfl_xor(ssum, 1, 64);
    ssum += __shfl_xor(ssum, 2, 64);
    ssum += __shfl_xor(ssum, 4, 64);
    ssum += __shfl_xor(ssum, 8, 64);
    ssum += pself;

    float v = acc / (ssum + 1e-16f) + bias[lane];
    v = (v - mean[lane]) * rsqrtf(var[lane] + BNEPS) * gamma[lane] + beta[lane];
    if (DOELU) v = v > 0.f ? v : __expf(v) - 1.f;
    if (DOPOOL) psum += v;
    else out[(size_t)node * 64 + lane] = v;
  }

  if constexpr (DOPOOL) {
    __shared__ float red[4][64];
    red[threadIdx.x >> 6][lane] = psum;
    __syncthreads();
    if (threadIdx.x < 64)
      atomicAdd(&pooled[lane], red[0][lane] + red[1][lane] + red[2][lane] + red[3][lane]);
  }
}

// ---------------- MLP heads ----------------
__global__ void k_head(const float* __restrict__ pooled,
                       const float* __restrict__ cw1, const float* __restrict__ cb1,
                       const float* __restrict__ cw2, const float* __restrict__ cb2,
                       const float* __restrict__ rw1, const float* __restrict__ rb1,
                       const float* __restrict__ rw2, const float* __restrict__ rb2,
                       float* __restrict__ outp, float invN) {
  __shared__ float ps[64], hc[32], hr[32];
  int t = threadIdx.x;
  ps[t] = pooled[t] * invN;
  __syncthreads();
  if (t < 32) {
    float sc = cb1[t], sr = rb1[t];
    for (int c = 0; c < 64; ++c) {
      sc += ps[c] * cw1[t * 64 + c];
      sr += ps[c] * rw1[t * 64 + c];
    }
    hc[t] = sc > 0.f ? sc : 0.f;
    hr[t] = sr > 0.f ? sr : 0.f;
  }
  __syncthreads();
  if (t < 3) {
    float v = cb2[t];
    for (int j = 0; j < 32; ++j) v += hc[j] * cw2[t * 32 + j];
    outp[t] = v;
  } else if (t == 3) {
    float v = rb2[0];
    for (int j = 0; j < 32; ++j) v += hr[j] * rw2[j];
    outp[3] = v;
  }
}

static inline size_t align256(size_t x) { return (x + 255) & ~(size_t)255; }

extern "C" void kernel_launch(void* const* d_in, const int* in_sizes, int n_in,
                              void* d_out, int out_size, void* d_ws, size_t ws_size,
                              hipStream_t stream) {
  const float* x   = (const float*)d_in[0];
  const int*   ei  = (const int*)d_in[1];
  const float* W1  = (const float*)d_in[2];
  const float* a1s = (const float*)d_in[3];
  const float* a1d = (const float*)d_in[4];
  const float* b1  = (const float*)d_in[5];
  const float* W2  = (const float*)d_in[6];
  const float* a2s = (const float*)d_in[7];
  const float* a2d = (const float*)d_in[8];
  const float* b2  = (const float*)d_in[9];
  const float* W3  = (const float*)d_in[10];
  const float* a3s = (const float*)d_in[11];
  const float* a3d = (const float*)d_in[12];
  const float* b3  = (const float*)d_in[13];
  const float* bng = (const float*)d_in[14];
  const float* bnb = (const float*)d_in[15];
  const float* bnm = (const float*)d_in[16];
  const float* bnv = (const float*)d_in[17];
  const float* cw1 = (const float*)d_in[18];
  const float* cb1 = (const float*)d_in[19];
  const float* cw2 = (const float*)d_in[20];
  const float* cb2 = (const float*)d_in[21];
  const float* rw1 = (const float*)d_in[22];
  const float* rb1 = (const float*)d_in[23];
  const float* rw2 = (const float*)d_in[24];
  const float* rb2 = (const float*)d_in[25];

  const int N = in_sizes[0] / 5;
  const int E = in_sizes[1] / 2;
  const int* srcp = ei;
  const int* dstp = ei + E;
  const int NB = (N + 1023) >> 10;

  // workspace carve-up
  char* p = (char*)d_ws;
  int* rowstart   = (int*)p;  p += align256((size_t)(N + 1) * 4);
  int* csr        = (int*)p;  p += align256((size_t)E * 4);
  int* bcnt       = (int*)p;  p += align256(BK * 4);
  int* bucketBase = (int*)p;  p += align256((BK + 1) * 4);
  int* cursorB    = (int*)p;  p += align256(BK * 4);
  __half* hH    = (__half*)p; p += align256((size_t)N * 64 * 2);   // fp16 gather buffer
  float* hB     = (float*)p;  p += align256((size_t)N * 64 * 4);   // fp32 agg output
  float* alsrc  = (float*)p;  p += align256((size_t)N * 4 * 4);
  float* aldst  = (float*)p;  p += align256((size_t)N * 4 * 4);
  float* pooled = (float*)p;  p += align256(64 * 4);
  float* outp   = (float*)d_out;
  // staging for bucket sort aliases hB (12.8 MB < 25.6 MB; dead until k_agg L1)
  int2* stg     = (int2*)hB;

  hipMemsetAsync(bcnt, 0, BK * 4, stream);
  hipMemsetAsync(pooled, 0, 64 * 4, stream);

  k_count<<<512, 256, 0, stream>>>(dstp, bcnt, E);
  k_bscan<<<1, BK, 0, stream>>>(bcnt, bucketBase, cursorB, E);
  k_bucket<<<(E + TILE - 1) / TILE, 256, 0, stream>>>(srcp, dstp, cursorB, stg, E);
  k_fine<<<NB, 256, 0, stream>>>(stg, bucketBase, rowstart, csr, N, NB);

  const int gNode4 = (N + 3) / 4;
  const int gNode128 = (N + 127) / 128;

  // Layer 1: x -> hH ; agg -> hB
  k_gemm_l1<<<gNode4, 256, 0, stream>>>(x, W1, a1s, a1d, hH, alsrc, aldst, N);
  k_agg<4, true, false><<<gNode4, 256, 0, stream>>>(hH, alsrc, aldst, rowstart, csr,
      b1, bng + 0, bnb + 0, bnm + 0, bnv + 0, hB, nullptr, N);

  // Layer 2: hB -> hH ; agg -> hB
  k_gemm64<4><<<gNode128, 256, 0, stream>>>(hB, W2, a2s, a2d, hH, alsrc, aldst, N);
  k_agg<4, true, false><<<gNode4, 256, 0, stream>>>(hH, alsrc, aldst, rowstart, csr,
      b2, bng + 64, bnb + 64, bnm + 64, bnv + 64, hB, nullptr, N);

  // Layer 3: hB -> hH ; agg fused with mean-pool (no hB write)
  k_gemm64<1><<<gNode128, 256, 0, stream>>>(hB, W3, a3s, a3d, hH, alsrc, aldst, N);
  k_agg<1, false, true><<<2048, 256, 0, stream>>>(hH, alsrc, aldst, rowstart, csr,
      b3, bng + 128, bnb + 128, bnm + 128, bnv + 128, nullptr, pooled, N);

  k_head<<<1, 64, 0, stream>>>(pooled, cw1, cb1, cw2, cb2, rw1, rb1, rw2, rb2,
                               outp, 1.0f / (float)N);
}